// Round 4
// baseline (178.200 us; speedup 1.0000x reference)
//
#include <hip/hip_runtime.h>
#include <math.h>

typedef __attribute__((ext_vector_type(8))) short bf16x8;
typedef __attribute__((ext_vector_type(4))) float f32x4;

#define AAM_COS_M 0.9800665778412416f
#define AAM_SIN_M 0.19866933079506122f
#define AAM_TH   (-0.9800665778412416f)
#define AAM_MM    0.03973386615901225f
#define C_CLS 5994

__device__ inline ushort f2bf(float f) {
    unsigned x = __float_as_uint(f);
    return (ushort)((x + 0x7fffu + ((x >> 16) & 1u)) >> 16);
}
__device__ inline float bflo(unsigned u) { return __uint_as_float(u << 16); }
__device__ inline float bfhi(unsigned u) { return __uint_as_float(u & 0xffff0000u); }

// async global->LDS, 16B per lane. LDS dest must be wave-uniform base;
// HW writes base + lane*16 (m104). Global src is per-lane.
__device__ __forceinline__ void gload16(const void* g, void* lds) {
    __builtin_amdgcn_global_load_lds(
        (const __attribute__((address_space(1))) unsigned int*)g,
        (__attribute__((address_space(3))) unsigned int*)lds, 16, 0, 0);
}

// ---------------- fp32 -> bf16 for x (4096 blocks) and Wfc (256 blocks) ----
__global__ __launch_bounds__(256) void conv_bf16(const float* __restrict__ x,
                                                 const float* __restrict__ Wfc,
                                                 ushort* __restrict__ xb,
                                                 ushort* __restrict__ wb) {
    int b = blockIdx.x;
    const float* s; ushort* d; int i;
    if (b < 4096) { s = x; d = xb; i = b * 256 + threadIdx.x; }
    else          { s = Wfc; d = wb; i = (b - 4096) * 256 + threadIdx.x; }
    float4 v = ((const float4*)s)[i];
    ushort4 o;
    o.x = f2bf(v.x); o.y = f2bf(v.y); o.z = f2bf(v.z); o.w = f2bf(v.w);
    ((ushort4*)d)[i] = o;
}

// ---------------- fc GEMM: E = x @ Wfc^T + b ------------------------------
// M=4096,N=256,K=1024. 64x64 tile, grid (64,4)=256 blocks, 4 waves 2x2,
// each wave 32x32 (2x2 frags). Linear LDS [64][32] + global_load_lds.
__global__ __launch_bounds__(256) void fc_mfma(const ushort* __restrict__ A,
                                               const ushort* __restrict__ Bm,
                                               const float* __restrict__ bias,
                                               float* __restrict__ C) {
    __shared__ ushort As[64 * 32];
    __shared__ ushort Bs[64 * 32];
    const int tid = threadIdx.x, lane = tid & 63, w = tid >> 6;
    const int wr = w >> 1, wc = w & 1;
    const int lx = lane & 15, lg = lane >> 4;
    const int l4 = lane >> 2, c8 = (lane & 3) << 3;
    const int rb = blockIdx.x * 64, cb = blockIdx.y * 64;

    f32x4 zero = {0.f, 0.f, 0.f, 0.f};
    f32x4 acc[2][2];
#pragma unroll
    for (int i = 0; i < 2; ++i)
#pragma unroll
        for (int j = 0; j < 2; ++j) acc[i][j] = zero;

    for (int k0 = 0; k0 < 1024; k0 += 32) {
        // wave w stages rows [w*16, w*16+16) of each 64x32 tile (1 KB each)
        gload16(&A[(size_t)(rb + w * 16 + l4) * 1024 + k0 + c8], &As[w * 512]);
        gload16(&Bm[(size_t)(cb + w * 16 + l4) * 1024 + k0 + c8], &Bs[w * 512]);
        __syncthreads();
        bf16x8 af[2], bv[2];
#pragma unroll
        for (int f = 0; f < 2; ++f) {
            af[f] = *(const bf16x8*)&As[(wr * 32 + f * 16 + lx) * 32 + lg * 8];
            bv[f] = *(const bf16x8*)&Bs[(wc * 32 + f * 16 + lx) * 32 + lg * 8];
        }
#pragma unroll
        for (int i = 0; i < 2; ++i)
#pragma unroll
            for (int j = 0; j < 2; ++j)
                acc[i][j] = __builtin_amdgcn_mfma_f32_16x16x32_bf16(af[i], bv[j], acc[i][j], 0, 0, 0);
        __syncthreads();
    }
#pragma unroll
    for (int j = 0; j < 2; ++j) {
        int col = cb + wc * 32 + j * 16 + lx;
        float bb = bias[col];
#pragma unroll
        for (int i = 0; i < 2; ++i) {
            int row0 = rb + wr * 32 + i * 16 + lg * 4;
#pragma unroll
            for (int r = 0; r < 4; ++r)
                C[(size_t)(row0 + r) * 256 + col] = acc[i][j][r] + bb;
        }
    }
}

// ---------------- row L2-normalize E (fp32) -> bf16 -------------------------
__global__ __launch_bounds__(256) void rownorm_e(const float* __restrict__ E,
                                                 ushort* __restrict__ En) {
    const int wave = threadIdx.x >> 6, lane = threadIdx.x & 63;
    const int row = blockIdx.x * 4 + wave;
    float4 v = ((const float4*)&E[(size_t)row * 256])[lane];
    float ss = v.x * v.x + v.y * v.y + v.z * v.z + v.w * v.w;
#pragma unroll
    for (int m = 32; m >= 1; m >>= 1) ss += __shfl_xor(ss, m, 64);
    float sc = 1.f / fmaxf(sqrtf(ss), 1e-12f);
    ushort4 o;
    o.x = f2bf(v.x * sc); o.y = f2bf(v.y * sc); o.z = f2bf(v.z * sc); o.w = f2bf(v.w * sc);
    ((ushort4*)&En[(size_t)row * 256])[lane] = o;
}

// ---------------- row L2-normalize W_aam -> bf16, zero-pad to 6144 ----------
__global__ __launch_bounds__(256) void rownorm_w(const float* __restrict__ W,
                                                 ushort* __restrict__ Wn) {
    const int wave = threadIdx.x >> 6, lane = threadIdx.x & 63;
    const int row = blockIdx.x * 4 + wave;
    if (row >= 6144) return;
    ushort4 o;
    if (row < C_CLS) {
        float4 v = ((const float4*)&W[(size_t)row * 256])[lane];
        float ss = v.x * v.x + v.y * v.y + v.z * v.z + v.w * v.w;
#pragma unroll
        for (int m = 32; m >= 1; m >>= 1) ss += __shfl_xor(ss, m, 64);
        float sc = 1.f / fmaxf(sqrtf(ss), 1e-12f);
        o.x = f2bf(v.x * sc); o.y = f2bf(v.y * sc); o.z = f2bf(v.z * sc); o.w = f2bf(v.w * sc);
    } else {
        o.x = 0; o.y = 0; o.z = 0; o.w = 0;
    }
    ((ushort4*)&Wn[(size_t)row * 256])[lane] = o;
}

// ---------------- cosine GEMM + masked online softmax partials --------------
// M=4096, N=6144(pad), K=256. 128x128 tiles, grid (32,16)=512 blocks,
// 4 waves 2x2, each 64x64 (4x4 frags). Linear LDS [128][32] + global_load_lds.
__global__ __launch_bounds__(256) void aam_mfma(const ushort* __restrict__ A,
                                                const ushort* __restrict__ Bm,
                                                float* __restrict__ pm,
                                                float* __restrict__ ps) {
    __shared__ ushort As[128 * 32];
    __shared__ ushort Bs[128 * 32];
    const int tid = threadIdx.x, lane = tid & 63, w = tid >> 6;
    const int wr = w >> 1, wc = w & 1;
    const int lx = lane & 15, lg = lane >> 4;
    const int l4 = lane >> 2, c8 = (lane & 3) << 3;
    const int rb = blockIdx.x * 128;
    const int split = blockIdx.y;

    float mrun[16], srun[16];
#pragma unroll
    for (int idx = 0; idx < 16; ++idx) { mrun[idx] = -INFINITY; srun[idx] = 0.f; }

    f32x4 zero = {0.f, 0.f, 0.f, 0.f};
    for (int t = 0; t < 3; ++t) {
        const int cb = split * 384 + t * 128;
        f32x4 acc[4][4];
#pragma unroll
        for (int i = 0; i < 4; ++i)
#pragma unroll
            for (int j = 0; j < 4; ++j) acc[i][j] = zero;

        for (int k0 = 0; k0 < 256; k0 += 32) {
            // wave w stages rows [w*32, w*32+32) of each 128x32 tile (2x1KB each)
            gload16(&A[(size_t)(rb + w * 32 + l4) * 256 + k0 + c8], &As[w * 1024]);
            gload16(&A[(size_t)(rb + w * 32 + 16 + l4) * 256 + k0 + c8], &As[w * 1024 + 512]);
            gload16(&Bm[(size_t)(cb + w * 32 + l4) * 256 + k0 + c8], &Bs[w * 1024]);
            gload16(&Bm[(size_t)(cb + w * 32 + 16 + l4) * 256 + k0 + c8], &Bs[w * 1024 + 512]);
            __syncthreads();
            bf16x8 af[4], bv[4];
#pragma unroll
            for (int f = 0; f < 4; ++f) {
                af[f] = *(const bf16x8*)&As[(wr * 64 + f * 16 + lx) * 32 + lg * 8];
                bv[f] = *(const bf16x8*)&Bs[(wc * 64 + f * 16 + lx) * 32 + lg * 8];
            }
#pragma unroll
            for (int i = 0; i < 4; ++i)
#pragma unroll
                for (int j = 0; j < 4; ++j)
                    acc[i][j] = __builtin_amdgcn_mfma_f32_16x16x32_bf16(af[i], bv[j], acc[i][j], 0, 0, 0);
            __syncthreads();
        }

        // masked online softmax accumulate (plain cosine logits)
#pragma unroll
        for (int j = 0; j < 4; ++j) {
            int c = cb + wc * 64 + j * 16 + lx;
            if (c < C_CLS) {
#pragma unroll
                for (int i = 0; i < 4; ++i)
#pragma unroll
                    for (int r = 0; r < 4; ++r) {
                        float v = 30.f * acc[i][j][r];
                        int idx = i * 4 + r;
                        float mn = fmaxf(mrun[idx], v);
                        srun[idx] = srun[idx] * __expf(mrun[idx] - mn) + __expf(v - mn);
                        mrun[idx] = mn;
                    }
            }
        }
    }

    // reduce over the 16 lanes (lx) sharing each row
#pragma unroll
    for (int idx = 0; idx < 16; ++idx) {
#pragma unroll
        for (int msk = 1; msk < 16; msk <<= 1) {
            float om = __shfl_xor(mrun[idx], msk, 64);
            float os = __shfl_xor(srun[idx], msk, 64);
            float mn = fmaxf(mrun[idx], om);
            float sa = (mrun[idx] > -1e37f) ? srun[idx] * __expf(mrun[idx] - mn) : 0.f;
            float sb = (om > -1e37f) ? os * __expf(om - mn) : 0.f;
            mrun[idx] = mn; srun[idx] = sa + sb;
        }
        if (lx == 0) {
            int row = rb + wr * 64 + (idx >> 2) * 16 + lg * 4 + (idx & 3);
            int part = split * 2 + wc;           // 32 partials per row
            pm[part * 4096 + row] = mrun[idx];
            ps[part * 4096 + row] = srun[idx];
        }
    }
}

// ---------------- fused: label-dot + merge 32 partials + margin + nll -------
// One wave per row: 64 lanes compute dot(En[row], Wn[label]) and wave-parallel
// merge of the 32 softmax partials, then lane 0 applies margin + atomicAdd.
__global__ __launch_bounds__(256) void reduce_all(const float* __restrict__ pm,
                                                  const float* __restrict__ ps,
                                                  const ushort* __restrict__ En,
                                                  const ushort* __restrict__ Wn,
                                                  const int* __restrict__ lab,
                                                  float* __restrict__ out) {
    const int wave = threadIdx.x >> 6, lane = threadIdx.x & 63;
    const int row = blockIdx.x * 4 + wave;
    const int l = lab[row];
    uint2 a = ((const uint2*)&En[(size_t)row * 256])[lane];
    uint2 b = ((const uint2*)&Wn[(size_t)l * 256])[lane];
    float sum = bflo(a.x) * bflo(b.x) + bfhi(a.x) * bfhi(b.x)
              + bflo(a.y) * bflo(b.y) + bfhi(a.y) * bfhi(b.y);
#pragma unroll
    for (int m = 32; m >= 1; m >>= 1) sum += __shfl_xor(sum, m, 64);
    float cv = sum;   // all lanes

    float m, s;
    if (lane < 32) { m = pm[lane * 4096 + row]; s = ps[lane * 4096 + row]; }
    else           { m = -INFINITY; s = 0.f; }
#pragma unroll
    for (int msk = 1; msk <= 32; msk <<= 1) {
        float om = __shfl_xor(m, msk, 64);
        float os = __shfl_xor(s, msk, 64);
        float mn = fmaxf(m, om);
        float sa = (m > -1e37f) ? s * __expf(m - mn) : 0.f;
        float sb = (om > -1e37f) ? os * __expf(om - mn) : 0.f;
        m = mn; s = sa + sb;
    }
    if (lane == 0) {
        float sine = sqrtf(fmaxf(1.f - cv * cv, 0.f));
        float phi = cv * AAM_COS_M - sine * AAM_SIN_M;
        phi = ((cv - AAM_TH) > 0.f) ? phi : (cv - AAM_MM);
        float vplain = 30.f * cv, vlab = 30.f * phi;
        float denom = s - __expf(vplain - m) + __expf(vlab - m);
        float nll = m + logf(denom) - vlab;
        atomicAdd(out, nll * (1.f / 4096.f));
    }
}

extern "C" void kernel_launch(void* const* d_in, const int* in_sizes, int n_in,
                              void* d_out, int out_size, void* d_ws, size_t ws_size,
                              hipStream_t stream) {
    const float* x    = (const float*)d_in[0];
    const int*   lab  = (const int*)d_in[1];
    const float* Wfc  = (const float*)d_in[2];
    const float* bfc  = (const float*)d_in[3];
    const float* Waam = (const float*)d_in[4];
    float* out = (float*)d_out;

    char* ws = (char*)d_ws;
    ushort* xb   = (ushort*)(ws);                 // 8 MB   [0, 8388608)
    ushort* Wfcb = (ushort*)(ws + 8388608);       // 512 KB
    float*  E    = (float*) (ws + 8912896);       // 4 MB
    ushort* En   = (ushort*)(ws);                 // 2 MB   overlay on dead xb
    ushort* Wn   = (ushort*)(ws + 2097152);       // 3 MB   overlay on dead xb
    float*  pm   = (float*) (ws + 13107200);      // 512 KB (32 parts x 4096)
    float*  ps   = (float*) (ws + 13631488);      // 512 KB

    conv_bf16<<<4352, 256, 0, stream>>>(x, Wfc, xb, Wfcb);
    fc_mfma<<<dim3(64, 4), 256, 0, stream>>>(xb, Wfcb, bfc, E);
    rownorm_e<<<1024, 256, 0, stream>>>(E, En);
    rownorm_w<<<1536, 256, 0, stream>>>(Waam, Wn);
    aam_mfma<<<dim3(32, 16), 256, 0, stream>>>(En, Wn, pm, ps);
    hipMemsetAsync(d_out, 0, sizeof(float), stream);
    reduce_all<<<1024, 256, 0, stream>>>(pm, ps, En, Wn, lab, out);
}

// Round 6
// 129.812 us; speedup vs baseline: 1.3728x; 1.3728x over previous
//
#include <hip/hip_runtime.h>
#include <math.h>

typedef __attribute__((ext_vector_type(8))) short bf16x8;
typedef __attribute__((ext_vector_type(4))) float f32x4;

#define AAM_COS_M 0.9800665778412416f
#define AAM_SIN_M 0.19866933079506122f
#define AAM_TH   (-0.9800665778412416f)
#define AAM_MM    0.03973386615901225f
#define C_CLS 5994

__device__ inline ushort f2bf(float f) {
    unsigned x = __float_as_uint(f);
    return (ushort)((x + 0x7fffu + ((x >> 16) & 1u)) >> 16);
}
__device__ inline float bflo(unsigned u) { return __uint_as_float(u << 16); }
__device__ inline float bfhi(unsigned u) { return __uint_as_float(u & 0xffff0000u); }

// async global->LDS, 16B per lane. LDS dest is wave-uniform base + lane*16.
__device__ __forceinline__ void gload16(const void* g, void* lds) {
    __builtin_amdgcn_global_load_lds(
        (const __attribute__((address_space(1))) unsigned int*)g,
        (__attribute__((address_space(3))) unsigned int*)lds, 16, 0, 0);
}

// ---------------- fp32 -> bf16 for x (4096 blocks) and Wfc (256 blocks) ----
__global__ __launch_bounds__(256) void conv_bf16(const float* __restrict__ x,
                                                 const float* __restrict__ Wfc,
                                                 ushort* __restrict__ xb,
                                                 ushort* __restrict__ wb) {
    int b = blockIdx.x;
    const float* s; ushort* d; int i;
    if (b < 4096) { s = x; d = xb; i = b * 256 + threadIdx.x; }
    else          { s = Wfc; d = wb; i = (b - 4096) * 256 + threadIdx.x; }
    float4 v = ((const float4*)s)[i];
    ushort4 o;
    o.x = f2bf(v.x); o.y = f2bf(v.y); o.z = f2bf(v.z); o.w = f2bf(v.w);
    ((ushort4*)d)[i] = o;
}

// ---------------- fc GEMM: E = x @ Wfc^T + b ------------------------------
// M=4096,N=256,K=1024. 64x64 tile, grid (64,4)=256 blocks, 4 waves 2x2,
// each wave 32x32 (2x2 frags). Linear LDS [64][32] + global_load_lds.
__global__ __launch_bounds__(256) void fc_mfma(const ushort* __restrict__ A,
                                               const ushort* __restrict__ Bm,
                                               const float* __restrict__ bias,
                                               float* __restrict__ C) {
    __shared__ ushort As[64 * 32];
    __shared__ ushort Bs[64 * 32];
    const int tid = threadIdx.x, lane = tid & 63, w = tid >> 6;
    const int wr = w >> 1, wc = w & 1;
    const int lx = lane & 15, lg = lane >> 4;
    const int l4 = lane >> 2, c8 = (lane & 3) << 3;
    const int rb = blockIdx.x * 64, cb = blockIdx.y * 64;

    f32x4 zero = {0.f, 0.f, 0.f, 0.f};
    f32x4 acc[2][2];
#pragma unroll
    for (int i = 0; i < 2; ++i)
#pragma unroll
        for (int j = 0; j < 2; ++j) acc[i][j] = zero;

    for (int k0 = 0; k0 < 1024; k0 += 32) {
        gload16(&A[(size_t)(rb + w * 16 + l4) * 1024 + k0 + c8], &As[w * 512]);
        gload16(&Bm[(size_t)(cb + w * 16 + l4) * 1024 + k0 + c8], &Bs[w * 512]);
        __syncthreads();
        bf16x8 af[2], bv[2];
#pragma unroll
        for (int f = 0; f < 2; ++f) {
            af[f] = *(const bf16x8*)&As[(wr * 32 + f * 16 + lx) * 32 + lg * 8];
            bv[f] = *(const bf16x8*)&Bs[(wc * 32 + f * 16 + lx) * 32 + lg * 8];
        }
#pragma unroll
        for (int i = 0; i < 2; ++i)
#pragma unroll
            for (int j = 0; j < 2; ++j)
                acc[i][j] = __builtin_amdgcn_mfma_f32_16x16x32_bf16(af[i], bv[j], acc[i][j], 0, 0, 0);
        __syncthreads();
    }
#pragma unroll
    for (int j = 0; j < 2; ++j) {
        int col = cb + wc * 32 + j * 16 + lx;
        float bb = bias[col];
#pragma unroll
        for (int i = 0; i < 2; ++i) {
            int row0 = rb + wr * 32 + i * 16 + lg * 4;
#pragma unroll
            for (int r = 0; r < 4; ++r)
                C[(size_t)(row0 + r) * 256 + col] = acc[i][j][r] + bb;
        }
    }
}

// ---------------- row L2-normalize E (fp32) -> bf16 -------------------------
__global__ __launch_bounds__(256) void rownorm_e(const float* __restrict__ E,
                                                 ushort* __restrict__ En) {
    const int wave = threadIdx.x >> 6, lane = threadIdx.x & 63;
    const int row = blockIdx.x * 4 + wave;
    float4 v = ((const float4*)&E[(size_t)row * 256])[lane];
    float ss = v.x * v.x + v.y * v.y + v.z * v.z + v.w * v.w;
#pragma unroll
    for (int m = 32; m >= 1; m >>= 1) ss += __shfl_xor(ss, m, 64);
    float sc = 1.f / fmaxf(sqrtf(ss), 1e-12f);
    ushort4 o;
    o.x = f2bf(v.x * sc); o.y = f2bf(v.y * sc); o.z = f2bf(v.z * sc); o.w = f2bf(v.w * sc);
    ((ushort4*)&En[(size_t)row * 256])[lane] = o;
}

// ---------------- row L2-normalize W_aam -> bf16, zero-pad to 6144 ----------
__global__ __launch_bounds__(256) void rownorm_w(const float* __restrict__ W,
                                                 ushort* __restrict__ Wn) {
    const int wave = threadIdx.x >> 6, lane = threadIdx.x & 63;
    const int row = blockIdx.x * 4 + wave;
    if (row >= 6144) return;
    ushort4 o;
    if (row < C_CLS) {
        float4 v = ((const float4*)&W[(size_t)row * 256])[lane];
        float ss = v.x * v.x + v.y * v.y + v.z * v.z + v.w * v.w;
#pragma unroll
        for (int m = 32; m >= 1; m >>= 1) ss += __shfl_xor(ss, m, 64);
        float sc = 1.f / fmaxf(sqrtf(ss), 1e-12f);
        o.x = f2bf(v.x * sc); o.y = f2bf(v.y * sc); o.z = f2bf(v.z * sc); o.w = f2bf(v.w * sc);
    } else {
        o.x = 0; o.y = 0; o.z = 0; o.w = 0;
    }
    ((ushort4*)&Wn[(size_t)row * 256])[lane] = o;
}

// ---------------- cosine GEMM + masked online softmax partials --------------
// M=4096, N=6144(pad), K=256. 128x128 tiles, grid (32,16)=512 blocks,
// 4 waves 2x2, each 64x64 (4x4 frags). Linear LDS [128][32] + global_load_lds.
__global__ __launch_bounds__(256) void aam_mfma(const ushort* __restrict__ A,
                                                const ushort* __restrict__ Bm,
                                                float* __restrict__ pm,
                                                float* __restrict__ ps) {
    __shared__ ushort As[128 * 32];
    __shared__ ushort Bs[128 * 32];
    const int tid = threadIdx.x, lane = tid & 63, w = tid >> 6;
    const int wr = w >> 1, wc = w & 1;
    const int lx = lane & 15, lg = lane >> 4;
    const int l4 = lane >> 2, c8 = (lane & 3) << 3;
    const int rb = blockIdx.x * 128;
    const int split = blockIdx.y;

    float mrun[16], srun[16];
#pragma unroll
    for (int idx = 0; idx < 16; ++idx) { mrun[idx] = -INFINITY; srun[idx] = 0.f; }

    f32x4 zero = {0.f, 0.f, 0.f, 0.f};
    for (int t = 0; t < 3; ++t) {
        const int cb = split * 384 + t * 128;
        f32x4 acc[4][4];
#pragma unroll
        for (int i = 0; i < 4; ++i)
#pragma unroll
            for (int j = 0; j < 4; ++j) acc[i][j] = zero;

        for (int k0 = 0; k0 < 256; k0 += 32) {
            gload16(&A[(size_t)(rb + w * 32 + l4) * 256 + k0 + c8], &As[w * 1024]);
            gload16(&A[(size_t)(rb + w * 32 + 16 + l4) * 256 + k0 + c8], &As[w * 1024 + 512]);
            gload16(&Bm[(size_t)(cb + w * 32 + l4) * 256 + k0 + c8], &Bs[w * 1024]);
            gload16(&Bm[(size_t)(cb + w * 32 + 16 + l4) * 256 + k0 + c8], &Bs[w * 1024 + 512]);
            __syncthreads();
            bf16x8 af[4], bv[4];
#pragma unroll
            for (int f = 0; f < 4; ++f) {
                af[f] = *(const bf16x8*)&As[(wr * 64 + f * 16 + lx) * 32 + lg * 8];
                bv[f] = *(const bf16x8*)&Bs[(wc * 64 + f * 16 + lx) * 32 + lg * 8];
            }
#pragma unroll
            for (int i = 0; i < 4; ++i)
#pragma unroll
                for (int j = 0; j < 4; ++j)
                    acc[i][j] = __builtin_amdgcn_mfma_f32_16x16x32_bf16(af[i], bv[j], acc[i][j], 0, 0, 0);
            __syncthreads();
        }

#pragma unroll
        for (int j = 0; j < 4; ++j) {
            int c = cb + wc * 64 + j * 16 + lx;
            if (c < C_CLS) {
#pragma unroll
                for (int i = 0; i < 4; ++i)
#pragma unroll
                    for (int r = 0; r < 4; ++r) {
                        float v = 30.f * acc[i][j][r];
                        int idx = i * 4 + r;
                        float mn = fmaxf(mrun[idx], v);
                        srun[idx] = srun[idx] * __expf(mrun[idx] - mn) + __expf(v - mn);
                        mrun[idx] = mn;
                    }
            }
        }
    }

#pragma unroll
    for (int idx = 0; idx < 16; ++idx) {
#pragma unroll
        for (int msk = 1; msk < 16; msk <<= 1) {
            float om = __shfl_xor(mrun[idx], msk, 64);
            float os = __shfl_xor(srun[idx], msk, 64);
            float mn = fmaxf(mrun[idx], om);
            float sa = (mrun[idx] > -1e37f) ? srun[idx] * __expf(mrun[idx] - mn) : 0.f;
            float sb = (om > -1e37f) ? os * __expf(om - mn) : 0.f;
            mrun[idx] = mn; srun[idx] = sa + sb;
        }
        if (lx == 0) {
            int row = rb + wr * 64 + (idx >> 2) * 16 + lg * 4 + (idx & 3);
            int part = split * 2 + wc;           // 32 partials per row
            pm[part * 4096 + row] = mrun[idx];
            ps[part * 4096 + row] = srun[idx];
        }
    }
}

// ---------------- stage 1: per-row nll, block-partial sums (NO atomics) -----
// 256 blocks x 256 thr. Each wave handles 4 rows; block writes ONE partial.
__global__ __launch_bounds__(256) void reduce_all(const float* __restrict__ pm,
                                                  const float* __restrict__ ps,
                                                  const ushort* __restrict__ En,
                                                  const ushort* __restrict__ Wn,
                                                  const int* __restrict__ lab,
                                                  float* __restrict__ partial) {
    __shared__ float red[4];
    const int wave = threadIdx.x >> 6, lane = threadIdx.x & 63;
    const int gw = blockIdx.x * 4 + wave;      // 1024 waves, 4 rows each
    float acc = 0.f;
#pragma unroll
    for (int r = 0; r < 4; ++r) {
        const int row = gw * 4 + r;
        const int l = lab[row];
        uint2 a = ((const uint2*)&En[(size_t)row * 256])[lane];
        uint2 b = ((const uint2*)&Wn[(size_t)l * 256])[lane];
        float sum = bflo(a.x) * bflo(b.x) + bfhi(a.x) * bfhi(b.x)
                  + bflo(a.y) * bflo(b.y) + bfhi(a.y) * bfhi(b.y);
#pragma unroll
        for (int m = 32; m >= 1; m >>= 1) sum += __shfl_xor(sum, m, 64);
        float cv = sum;   // all lanes

        float m, s;
        if (lane < 32) { m = pm[lane * 4096 + row]; s = ps[lane * 4096 + row]; }
        else           { m = -INFINITY; s = 0.f; }
#pragma unroll
        for (int msk = 1; msk <= 32; msk <<= 1) {
            float om = __shfl_xor(m, msk, 64);
            float os = __shfl_xor(s, msk, 64);
            float mn = fmaxf(m, om);
            float sa = (m > -1e37f) ? s * __expf(m - mn) : 0.f;
            float sb = (om > -1e37f) ? os * __expf(om - mn) : 0.f;
            m = mn; s = sa + sb;
        }
        // all lanes now hold merged (m,s); lane-uniform margin math
        float sine = sqrtf(fmaxf(1.f - cv * cv, 0.f));
        float phi = cv * AAM_COS_M - sine * AAM_SIN_M;
        phi = ((cv - AAM_TH) > 0.f) ? phi : (cv - AAM_MM);
        float vplain = 30.f * cv, vlab = 30.f * phi;
        float denom = s - __expf(vplain - m) + __expf(vlab - m);
        acc += m + logf(denom) - vlab;
    }
    if (lane == 0) red[wave] = acc;
    __syncthreads();
    if (threadIdx.x == 0)
        partial[blockIdx.x] = red[0] + red[1] + red[2] + red[3];
}

// ---------------- stage 2: sum 256 partials -> mean, overwrite d_out --------
__global__ __launch_bounds__(256) void final_reduce(const float* __restrict__ partial,
                                                    float* __restrict__ out) {
    __shared__ float red[4];
    const int wave = threadIdx.x >> 6, lane = threadIdx.x & 63;
    float v = partial[threadIdx.x];
#pragma unroll
    for (int m = 32; m >= 1; m >>= 1) v += __shfl_xor(v, m, 64);
    if (lane == 0) red[wave] = v;
    __syncthreads();
    if (threadIdx.x == 0)
        out[0] = (red[0] + red[1] + red[2] + red[3]) * (1.f / 4096.f);
}

extern "C" void kernel_launch(void* const* d_in, const int* in_sizes, int n_in,
                              void* d_out, int out_size, void* d_ws, size_t ws_size,
                              hipStream_t stream) {
    const float* x    = (const float*)d_in[0];
    const int*   lab  = (const int*)d_in[1];
    const float* Wfc  = (const float*)d_in[2];
    const float* bfc  = (const float*)d_in[3];
    const float* Waam = (const float*)d_in[4];
    float* out = (float*)d_out;

    char* ws = (char*)d_ws;
    ushort* xb   = (ushort*)(ws);                 // 8 MB   [0, 8388608)
    ushort* Wfcb = (ushort*)(ws + 8388608);       // 512 KB
    float*  E    = (float*) (ws + 8912896);       // 4 MB
    ushort* En   = (ushort*)(ws);                 // 2 MB   overlay on dead xb
    ushort* Wn   = (ushort*)(ws + 2097152);       // 3 MB   overlay on dead xb
    float*  pm   = (float*) (ws + 13107200);      // 512 KB (32 parts x 4096)
    float*  ps   = (float*) (ws + 13631488);      // 512 KB
    float*  part = (float*) (ws + 14155776);      // 1 KB   (256 block partials)

    conv_bf16<<<4352, 256, 0, stream>>>(x, Wfc, xb, Wfcb);
    fc_mfma<<<dim3(64, 4), 256, 0, stream>>>(xb, Wfcb, bfc, E);
    rownorm_e<<<1024, 256, 0, stream>>>(E, En);
    rownorm_w<<<1536, 256, 0, stream>>>(Waam, Wn);
    aam_mfma<<<dim3(32, 16), 256, 0, stream>>>(En, Wn, pm, ps);
    reduce_all<<<256, 256, 0, stream>>>(pm, ps, En, Wn, lab, part);
    final_reduce<<<1, 256, 0, stream>>>(part, out);
}

// Round 7
// 119.874 us; speedup vs baseline: 1.4866x; 1.0829x over previous
//
#include <hip/hip_runtime.h>
#include <math.h>

typedef __attribute__((ext_vector_type(8))) short bf16x8;
typedef __attribute__((ext_vector_type(4))) float f32x4;

#define AAM_COS_M 0.9800665778412416f
#define AAM_SIN_M 0.19866933079506122f
#define AAM_TH   (-0.9800665778412416f)
#define AAM_MM    0.03973386615901225f
#define C_CLS 5994

__device__ inline ushort f2bf(float f) {
    unsigned x = __float_as_uint(f);
    return (ushort)((x + 0x7fffu + ((x >> 16) & 1u)) >> 16);
}
__device__ inline float bflo(unsigned u) { return __uint_as_float(u << 16); }
__device__ inline float bfhi(unsigned u) { return __uint_as_float(u & 0xffff0000u); }

// async global->LDS, 16B per lane. LDS dest is wave-uniform base + lane*16.
__device__ __forceinline__ void gload16(const void* g, void* lds) {
    __builtin_amdgcn_global_load_lds(
        (const __attribute__((address_space(1))) unsigned int*)g,
        (__attribute__((address_space(3))) unsigned int*)lds, 16, 0, 0);
}

// ---------------- prep: x->bf16 (4096 blk), Wfc->bf16 (256 blk),
//                  rownorm_w+pad (1536 blk). One dispatch. -------------------
__global__ __launch_bounds__(256) void prep(const float* __restrict__ x,
                                            const float* __restrict__ Wfc,
                                            const float* __restrict__ Waam,
                                            ushort* __restrict__ xb,
                                            ushort* __restrict__ wfcb,
                                            ushort* __restrict__ Wn) {
    const int b = blockIdx.x;
    if (b < 4352) {
        const float* s = (b < 4096) ? x : Wfc;
        ushort* d      = (b < 4096) ? xb : wfcb;
        int i = (b < 4096 ? b : b - 4096) * 256 + threadIdx.x;
        float4 v = ((const float4*)s)[i];
        ushort4 o;
        o.x = f2bf(v.x); o.y = f2bf(v.y); o.z = f2bf(v.z); o.w = f2bf(v.w);
        ((ushort4*)d)[i] = o;
    } else {
        const int wave = threadIdx.x >> 6, lane = threadIdx.x & 63;
        const int row = (b - 4352) * 4 + wave;
        ushort4 o;
        if (row < C_CLS) {
            float4 v = ((const float4*)&Waam[(size_t)row * 256])[lane];
            float ss = v.x * v.x + v.y * v.y + v.z * v.z + v.w * v.w;
#pragma unroll
            for (int m = 32; m >= 1; m >>= 1) ss += __shfl_xor(ss, m, 64);
            float sc = 1.f / fmaxf(sqrtf(ss), 1e-12f);
            o.x = f2bf(v.x * sc); o.y = f2bf(v.y * sc);
            o.z = f2bf(v.z * sc); o.w = f2bf(v.w * sc);
        } else {
            o.x = 0; o.y = 0; o.z = 0; o.w = 0;
        }
        ((ushort4*)&Wn[(size_t)row * 256])[lane] = o;
    }
}

// ---------------- fc GEMM: E = x @ Wfc^T + b (unchanged, proven) ------------
__global__ __launch_bounds__(256) void fc_mfma(const ushort* __restrict__ A,
                                               const ushort* __restrict__ Bm,
                                               const float* __restrict__ bias,
                                               float* __restrict__ C) {
    __shared__ ushort As[64 * 32];
    __shared__ ushort Bs[64 * 32];
    const int tid = threadIdx.x, lane = tid & 63, w = tid >> 6;
    const int wr = w >> 1, wc = w & 1;
    const int lx = lane & 15, lg = lane >> 4;
    const int l4 = lane >> 2, c8 = (lane & 3) << 3;
    const int rb = blockIdx.x * 64, cb = blockIdx.y * 64;

    f32x4 zero = {0.f, 0.f, 0.f, 0.f};
    f32x4 acc[2][2];
#pragma unroll
    for (int i = 0; i < 2; ++i)
#pragma unroll
        for (int j = 0; j < 2; ++j) acc[i][j] = zero;

    for (int k0 = 0; k0 < 1024; k0 += 32) {
        gload16(&A[(size_t)(rb + w * 16 + l4) * 1024 + k0 + c8], &As[w * 512]);
        gload16(&Bm[(size_t)(cb + w * 16 + l4) * 1024 + k0 + c8], &Bs[w * 512]);
        __syncthreads();
        bf16x8 af[2], bv[2];
#pragma unroll
        for (int f = 0; f < 2; ++f) {
            af[f] = *(const bf16x8*)&As[(wr * 32 + f * 16 + lx) * 32 + lg * 8];
            bv[f] = *(const bf16x8*)&Bs[(wc * 32 + f * 16 + lx) * 32 + lg * 8];
        }
#pragma unroll
        for (int i = 0; i < 2; ++i)
#pragma unroll
            for (int j = 0; j < 2; ++j)
                acc[i][j] = __builtin_amdgcn_mfma_f32_16x16x32_bf16(af[i], bv[j], acc[i][j], 0, 0, 0);
        __syncthreads();
    }
#pragma unroll
    for (int j = 0; j < 2; ++j) {
        int col = cb + wc * 32 + j * 16 + lx;
        float bb = bias[col];
#pragma unroll
        for (int i = 0; i < 2; ++i) {
            int row0 = rb + wr * 32 + i * 16 + lg * 4;
#pragma unroll
            for (int r = 0; r < 4; ++r)
                C[(size_t)(row0 + r) * 256 + col] = acc[i][j][r] + bb;
        }
    }
}

// ---------------- row L2-normalize E (fp32) -> bf16 -------------------------
__global__ __launch_bounds__(256) void rownorm_e(const float* __restrict__ E,
                                                 ushort* __restrict__ En) {
    const int wave = threadIdx.x >> 6, lane = threadIdx.x & 63;
    const int row = blockIdx.x * 4 + wave;
    float4 v = ((const float4*)&E[(size_t)row * 256])[lane];
    float ss = v.x * v.x + v.y * v.y + v.z * v.z + v.w * v.w;
#pragma unroll
    for (int m = 32; m >= 1; m >>= 1) ss += __shfl_xor(ss, m, 64);
    float sc = 1.f / fmaxf(sqrtf(ss), 1e-12f);
    ushort4 o;
    o.x = f2bf(v.x * sc); o.y = f2bf(v.y * sc); o.z = f2bf(v.z * sc); o.w = f2bf(v.w * sc);
    ((ushort4*)&En[(size_t)row * 256])[lane] = o;
}

// ---------------- cosine GEMM + exp-sum partials (fixed stabilizer m=30) ----
// M=4096, N=6144(pad), K=256. 128x128 tiles, BK=64, double-buffered 2-phase.
// Grid (32,16)=512 blocks, 4 waves 2x2, each 64x64 (4x4 frags).
// T2 swizzle: gload16 source col = ((l&7)^(l>>3))*8; read applies same XOR.
__global__ __launch_bounds__(256, 2) void aam_mfma(const ushort* __restrict__ A,
                                                   const ushort* __restrict__ Bm,
                                                   float* __restrict__ ps) {
    __shared__ ushort As[2][128 * 64];
    __shared__ ushort Bs[2][128 * 64];
    const int tid = threadIdx.x, lane = tid & 63, w = tid >> 6;
    const int wr = w >> 1, wc = w & 1;
    const int lx = lane & 15, lg = lane >> 4;
    const int rb = blockIdx.x * 128;
    const int split = blockIdx.y;

    // staging: lane covers row (lane>>3) within an 8-row group; 16B slot (lane&7).
    // global col pre-swizzled so LDS slot (row, c16) holds global slot c16^(row&7).
    const int lrow = lane >> 3;
    const int gcol = ((lane & 7) ^ lrow) * 8;

    float srun[16];
#pragma unroll
    for (int idx = 0; idx < 16; ++idx) srun[idx] = 0.f;

    f32x4 zero = {0.f, 0.f, 0.f, 0.f};
    f32x4 acc[4][4];
#pragma unroll
    for (int i = 0; i < 4; ++i)
#pragma unroll
        for (int j = 0; j < 4; ++j) acc[i][j] = zero;

#define AAM_STAGE(buf, g) do {                                                  \
    int t_ = (g) >> 2, k0_ = ((g) & 3) * 64;                                    \
    int cb_ = split * 384 + t_ * 128;                                           \
    _Pragma("unroll")                                                           \
    for (int s_ = 0; s_ < 4; ++s_) {                                            \
        int r0_ = w * 32 + s_ * 8;                                              \
        gload16(&A[(size_t)(rb + r0_ + lrow) * 256 + k0_ + gcol],               \
                &As[buf][r0_ * 64]);                                            \
        gload16(&Bm[(size_t)(cb_ + r0_ + lrow) * 256 + k0_ + gcol],             \
                &Bs[buf][r0_ * 64]);                                            \
    } } while (0)

    int cur = 0;
    AAM_STAGE(0, 0);
    __syncthreads();            // vmcnt(0) drain: buf0 ready

    for (int g = 0; g < 12; ++g) {
        if (g < 11) AAM_STAGE(cur ^ 1, g + 1);   // prefetch next step
#pragma unroll
        for (int kk = 0; kk < 2; ++kk) {
            bf16x8 af[4], bv[4];
#pragma unroll
            for (int f = 0; f < 4; ++f) {
                int ra = wr * 64 + f * 16 + lx;
                int ca = (lg + kk * 4) ^ (lx & 7);   // ra&7 == lx&7
                af[f] = *(const bf16x8*)&As[cur][ra * 64 + ca * 8];
                int rq = wc * 64 + f * 16 + lx;
                bv[f] = *(const bf16x8*)&Bs[cur][rq * 64 + ca * 8];
            }
#pragma unroll
            for (int i = 0; i < 4; ++i)
#pragma unroll
                for (int j = 0; j < 4; ++j)
                    acc[i][j] = __builtin_amdgcn_mfma_f32_16x16x32_bf16(af[i], bv[j], acc[i][j], 0, 0, 0);
        }
        if ((g & 3) == 3) {     // end of a 128-col tile: fold into exp-sums
            int cb_ = split * 384 + (g >> 2) * 128;
#pragma unroll
            for (int j = 0; j < 4; ++j) {
                int c = cb_ + wc * 64 + j * 16 + lx;
                if (c < C_CLS) {
#pragma unroll
                    for (int i = 0; i < 4; ++i)
#pragma unroll
                        for (int r = 0; r < 4; ++r)
                            srun[i * 4 + r] += __expf(30.f * acc[i][j][r] - 30.f);
                }
            }
#pragma unroll
            for (int i = 0; i < 4; ++i)
#pragma unroll
                for (int j = 0; j < 4; ++j) acc[i][j] = zero;
        }
        __syncthreads();        // drains prefetch (vmcnt) + protects buf reuse
        cur ^= 1;
    }
#undef AAM_STAGE

    // sum srun over the 16 lx-lanes sharing each row
#pragma unroll
    for (int idx = 0; idx < 16; ++idx) {
#pragma unroll
        for (int msk = 1; msk < 16; msk <<= 1)
            srun[idx] += __shfl_xor(srun[idx], msk, 64);
        if (lx == 0) {
            int row = rb + wr * 64 + (idx >> 2) * 16 + lg * 4 + (idx & 3);
            int part = split * 2 + wc;           // 32 partials per row
            ps[part * 4096 + row] = srun[idx];
        }
    }
}

// ---------------- stage 1: per-row nll, block-partial sums ------------------
__global__ __launch_bounds__(256) void reduce_all(const float* __restrict__ ps,
                                                  const ushort* __restrict__ En,
                                                  const ushort* __restrict__ Wn,
                                                  const int* __restrict__ lab,
                                                  float* __restrict__ partial) {
    __shared__ float red[4];
    const int wave = threadIdx.x >> 6, lane = threadIdx.x & 63;
    const int gw = blockIdx.x * 4 + wave;
    float acc = 0.f;
#pragma unroll
    for (int r = 0; r < 4; ++r) {
        const int row = gw * 4 + r;
        const int l = lab[row];
        uint2 a = ((const uint2*)&En[(size_t)row * 256])[lane];
        uint2 b = ((const uint2*)&Wn[(size_t)l * 256])[lane];
        float sum = bflo(a.x) * bflo(b.x) + bfhi(a.x) * bfhi(b.x)
                  + bflo(a.y) * bflo(b.y) + bfhi(a.y) * bfhi(b.y);
#pragma unroll
        for (int m = 32; m >= 1; m >>= 1) sum += __shfl_xor(sum, m, 64);
        float cv = sum;

        float s = (lane < 32) ? ps[lane * 4096 + row] : 0.f;
#pragma unroll
        for (int msk = 1; msk <= 32; msk <<= 1) s += __shfl_xor(s, msk, 64);

        float sine = sqrtf(fmaxf(1.f - cv * cv, 0.f));
        float phi = cv * AAM_COS_M - sine * AAM_SIN_M;
        phi = ((cv - AAM_TH) > 0.f) ? phi : (cv - AAM_MM);
        // s counted the label col with exp(30cv-30); swap for exp(30phi-30)
        float denom = s - __expf(30.f * cv - 30.f) + __expf(30.f * phi - 30.f);
        acc += 30.f + logf(denom) - 30.f * phi;
    }
    if (lane == 0) red[wave] = acc;
    __syncthreads();
    if (threadIdx.x == 0)
        partial[blockIdx.x] = red[0] + red[1] + red[2] + red[3];
}

// ---------------- stage 2: sum 256 partials -> mean -------------------------
__global__ __launch_bounds__(256) void final_reduce(const float* __restrict__ partial,
                                                    float* __restrict__ out) {
    __shared__ float red[4];
    const int wave = threadIdx.x >> 6, lane = threadIdx.x & 63;
    float v = partial[threadIdx.x];
#pragma unroll
    for (int m = 32; m >= 1; m >>= 1) v += __shfl_xor(v, m, 64);
    if (lane == 0) red[wave] = v;
    __syncthreads();
    if (threadIdx.x == 0)
        out[0] = (red[0] + red[1] + red[2] + red[3]) * (1.f / 4096.f);
}

extern "C" void kernel_launch(void* const* d_in, const int* in_sizes, int n_in,
                              void* d_out, int out_size, void* d_ws, size_t ws_size,
                              hipStream_t stream) {
    const float* x    = (const float*)d_in[0];
    const int*   lab  = (const int*)d_in[1];
    const float* Wfc  = (const float*)d_in[2];
    const float* bfc  = (const float*)d_in[3];
    const float* Waam = (const float*)d_in[4];
    float* out = (float*)d_out;

    char* ws = (char*)d_ws;
    ushort* xb   = (ushort*)(ws);                 // [0, 8388608)
    ushort* Wfcb = (ushort*)(ws + 8388608);       // [8388608, 8912896)
    float*  E    = (float*) (ws + 8912896);       // [8912896, 13107200)
    ushort* En   = (ushort*)(ws);                 // [0, 2097152) overlay dead xb
    ushort* Wn   = (ushort*)(ws + 13107200);      // [13107200, 16252928)
    float*  ps   = (float*) (ws + 16252928);      // [16252928, 16777216)
    float*  part = (float*) (ws + 16777216);      // 1 KB

    prep<<<5888, 256, 0, stream>>>(x, Wfc, Waam, xb, Wfcb, Wn);
    fc_mfma<<<dim3(64, 4), 256, 0, stream>>>(xb, Wfcb, bfc, E);
    rownorm_e<<<1024, 256, 0, stream>>>(E, En);
    aam_mfma<<<dim3(32, 16), 256, 0, stream>>>(En, Wn, ps);
    reduce_all<<<256, 256, 0, stream>>>(ps, En, Wn, lab, part);
    final_reduce<<<1, 256, 0, stream>>>(part, out);
}